// Round 3
// baseline (325.931 us; speedup 1.0000x reference)
//
#include <hip/hip_runtime.h>
#include <math.h>

#define IMG 512
#define TW 128     // output tile width
#define TH 16      // output tile height
#define ICOLS 144  // intermediate cols: global x0-8 .. x0+135 (8 = 2 full quads halo per side)
#define RS 148     // LDS row stride floats = 37 granules (odd -> per-row bank rotation)
#define NQ 36      // col-quads per intermediate row
#define NVT (NQ * TH)   // 576 vertical tasks (1 row x 4 cols each)
#define MMB 1024   // minmax stage-1 blocks

struct W11 { float w[11]; };

__device__ __forceinline__ unsigned omap(float f) {
  unsigned b = __float_as_uint(f);
  return (b & 0x80000000u) ? ~b : (b | 0x80000000u);
}
__device__ __forceinline__ float ounmap(unsigned u) {
  return __uint_as_float((u & 0x80000000u) ? (u ^ 0x80000000u) : ~u);
}

// Stage 1: per-block partial min/max -> disjoint slots, no atomics.
__global__ __launch_bounds__(256) void minmax_part(const float4* __restrict__ img,
                                                   int n4, unsigned* __restrict__ part) {
  unsigned mx = 0u, mn = 0xFFFFFFFFu;
  int stride = gridDim.x * blockDim.x;
  for (int i = blockIdx.x * blockDim.x + threadIdx.x; i < n4; i += stride) {
    float4 v = img[i];
    unsigned a = omap(v.x), b = omap(v.y), c = omap(v.z), d = omap(v.w);
    mx = max(mx, max(max(a, b), max(c, d)));
    mn = min(mn, min(min(a, b), min(c, d)));
  }
  #pragma unroll
  for (int off = 32; off > 0; off >>= 1) {
    mx = max(mx, __shfl_down(mx, off));
    mn = min(mn, __shfl_down(mn, off));
  }
  __shared__ unsigned smx[4], smn[4];
  int lane = threadIdx.x & 63, wv = threadIdx.x >> 6;
  if (lane == 0) { smx[wv] = mx; smn[wv] = mn; }
  __syncthreads();
  if (threadIdx.x == 0) {
    mx = max(max(smx[0], smx[1]), max(smx[2], smx[3]));
    mn = min(min(smn[0], smn[1]), min(smn[2], smn[3]));
    part[2 * blockIdx.x]     = mx;
    part[2 * blockIdx.x + 1] = mn;
  }
}

// Stage 2: fold MMB partial pairs into ws[0]=max, ws[1]=min.
__global__ __launch_bounds__(256) void minmax_final(const unsigned* __restrict__ part,
                                                    unsigned* __restrict__ ws) {
  unsigned mx = 0u, mn = 0xFFFFFFFFu;
  for (int i = threadIdx.x; i < MMB; i += 256) {
    mx = max(mx, part[2 * i]);
    mn = min(mn, part[2 * i + 1]);
  }
  #pragma unroll
  for (int off = 32; off > 0; off >>= 1) {
    mx = max(mx, __shfl_down(mx, off));
    mn = min(mn, __shfl_down(mn, off));
  }
  __shared__ unsigned smx[4], smn[4];
  int lane = threadIdx.x & 63, wv = threadIdx.x >> 6;
  if (lane == 0) { smx[wv] = mx; smn[wv] = mn; }
  __syncthreads();
  if (threadIdx.x == 0) {
    ws[0] = max(max(smx[0], smx[1]), max(smx[2], smx[3]));
    ws[1] = min(min(smn[0], smn[1]), min(smn[2], smn[3]));
  }
}

// Fused SSIM, v-first, phase-balanced: ALL 512 threads active in both passes
// (round-2 lesson: 128/320-thread h-pass collapsed occupancy to 17%).
// All LDS accesses are consecutive-lane -> consecutive-granule b128 (the only
// pattern measured conflict-free in round 0; round-2's same-start-bank reads
// cost 856 conflict-cycles/block).
// V-pass: 576 tasks of (1 intermediate row x 4 cols), register 11-tap v-conv of
// {a, b, a^2+b^2, a*b} (conv linear -> sigma1+sigma2 share one field).
// H-pass: thread = (1 row x 4 cols), 5 aligned b128 reads per field.
__global__ __launch_bounds__(512, 8) void ssim_k(const float* __restrict__ img1,
                                                 const float* __restrict__ img2,
                                                 float* __restrict__ out,
                                                 const unsigned* __restrict__ ws,
                                                 W11 wv) {
  __shared__ float V[4][TH][RS];   // 37888 B -> 4 blocks/CU; with VGPR<=64: 32 waves/CU

  const int tid = threadIdx.x;
  const int bx = blockIdx.x, by = blockIdx.y, n = blockIdx.z;
  const float* p1 = img1 + (size_t)n * IMG * IMG;
  const float* p2 = img2 + (size_t)n * IMG * IMG;
  const int x0 = bx * TW;
  const int y0 = by * TH;

  // C1/C2 (scalar loads issued early; needed after the barrier)
  float L = ounmap(ws[0]) - ounmap(ws[1]);
  if (L == 0.f) L = 5.f;
  float C1 = 0.01f * L; C1 *= C1;
  float C2 = 0.03f * L; C2 *= C2;

  const bool y_full = (by > 0) & (by < IMG / TH - 1);

  // ---- vertical pass: task t = (row r, col-quad q). 576 tasks on 512 threads:
  // everyone does task tid; every 8th thread also does task 512 + tid/8.
  #pragma unroll
  for (int s = 0; s < 2; ++s) {
    const bool active = (s == 0) | ((tid & 7) == 0);
    const int t = (s == 0) ? tid : (512 + (tid >> 3));
    if (active) {
      const unsigned r = (unsigned)t / 36u;       // 0..15
      const int q = t - (int)r * 36;              // 0..35
      const int gx0 = x0 - 8 + 4 * q;             // multiple of 4; quad fully in or fully out
      const int gy0 = y0 + (int)r - 5;

      float acc0x = 0.f, acc0y = 0.f, acc0z = 0.f, acc0w = 0.f;  // mu1 field
      float acc1x = 0.f, acc1y = 0.f, acc1z = 0.f, acc1w = 0.f;  // mu2 field
      float acc2x = 0.f, acc2y = 0.f, acc2z = 0.f, acc2w = 0.f;  // a^2+b^2
      float acc3x = 0.f, acc3y = 0.f, acc3z = 0.f, acc3w = 0.f;  // a*b

#define VSTEP(k, a, b)                                                        \
      {                                                                       \
        float wk = wv.w[k];                                                   \
        acc0x += wk * a.x; acc0y += wk * a.y; acc0z += wk * a.z; acc0w += wk * a.w; \
        acc1x += wk * b.x; acc1y += wk * b.y; acc1z += wk * b.z; acc1w += wk * b.w; \
        float sx = a.x * a.x + b.x * b.x, sy = a.y * a.y + b.y * b.y;         \
        float sz = a.z * a.z + b.z * b.z, sw = a.w * a.w + b.w * b.w;         \
        acc2x += wk * sx; acc2y += wk * sy; acc2z += wk * sz; acc2w += wk * sw; \
        float px = a.x * b.x, py = a.y * b.y, pz = a.z * b.z, pw = a.w * b.w; \
        acc3x += wk * px; acc3y += wk * py; acc3z += wk * pz; acc3w += wk * pw; \
      }

      if ((unsigned)gx0 < IMG) {   // in-range quad (halo quads are fully OOB -> zeros)
        if (y_full) {
          const float4* A = (const float4*)(p1 + (size_t)gy0 * IMG + gx0);
          const float4* B = (const float4*)(p2 + (size_t)gy0 * IMG + gx0);
          #pragma unroll
          for (int k = 0; k < 11; ++k) {
            float4 a = A[k * (IMG / 4)];
            float4 b = B[k * (IMG / 4)];
            VSTEP(k, a, b);
          }
        } else {
          #pragma unroll
          for (int k = 0; k < 11; ++k) {
            int row = gy0 + k;
            float4 a = make_float4(0.f, 0.f, 0.f, 0.f);
            float4 b = make_float4(0.f, 0.f, 0.f, 0.f);
            if ((unsigned)row < IMG) {
              a = *(const float4*)(p1 + (size_t)row * IMG + gx0);
              b = *(const float4*)(p2 + (size_t)row * IMG + gx0);
            }
            VSTEP(k, a, b);
          }
        }
      }
#undef VSTEP
      // b128 writes, consecutive lanes -> consecutive granules within a row
      *(float4*)&V[0][r][4 * q] = make_float4(acc0x, acc0y, acc0z, acc0w);
      *(float4*)&V[1][r][4 * q] = make_float4(acc1x, acc1y, acc1z, acc1w);
      *(float4*)&V[2][r][4 * q] = make_float4(acc2x, acc2y, acc2z, acc2w);
      *(float4*)&V[3][r][4 * q] = make_float4(acc3x, acc3y, acc3z, acc3w);
    }
  }
  __syncthreads();   // the only barrier

  // ---- horizontal pass: all 512 threads, thread = (row r, 4 output cols).
  // Lanes 0..31 of each wave read consecutive granules of one row (clean class);
  // the two half-waves are 37 granules apart (odd -> rotated bank phase).
  {
    const int r = tid >> 5;            // 0..15
    const int m = tid & 31;            // granule base within row
    const int c4 = m << 2;             // output col offset 0..124

    float acc[4][4];
    #pragma unroll
    for (int f = 0; f < 4; ++f)
      #pragma unroll
      for (int c = 0; c < 4; ++c) acc[f][c] = 0.f;

    float v[20];   // function scope, constant indices only (SROA-safe, round-1 lesson)
    #pragma unroll
    for (int f = 0; f < 4; ++f) {
      const float* row = &V[f][r][c4];
      float4 t0 = *(const float4*)(row + 0);
      float4 t1 = *(const float4*)(row + 4);
      float4 t2 = *(const float4*)(row + 8);
      float4 t3 = *(const float4*)(row + 12);
      float4 t4 = *(const float4*)(row + 16);
      v[0]  = t0.x; v[1]  = t0.y; v[2]  = t0.z; v[3]  = t0.w;
      v[4]  = t1.x; v[5]  = t1.y; v[6]  = t1.z; v[7]  = t1.w;
      v[8]  = t2.x; v[9]  = t2.y; v[10] = t2.z; v[11] = t2.w;
      v[12] = t3.x; v[13] = t3.y; v[14] = t3.z; v[15] = t3.w;
      v[16] = t4.x; v[17] = t4.y; v[18] = t4.z; v[19] = t4.w;
      // output col c taps intermediate local cols c4+c+3 .. c4+c+13 -> v[c+3+k]
      #pragma unroll
      for (int k = 0; k < 11; ++k) {
        float wk = wv.w[k];
        #pragma unroll
        for (int c = 0; c < 4; ++c) acc[f][c] += wk * v[c + 3 + k];
      }
    }

    float res[4];
    #pragma unroll
    for (int c = 0; c < 4; ++c) {
      float mu1 = acc[0][c], mu2 = acc[1][c];
      float mu1s = mu1 * mu1, mu2s = mu2 * mu2, mu12 = mu1 * mu2;
      float sS  = acc[2][c] - mu1s - mu2s;   // sigma1_sq + sigma2_sq
      float s12 = acc[3][c] - mu12;
      float num = (2.f * mu12 + C1) * (2.f * s12 + C2);
      float den = (mu1s + mu2s + C1) * (sS + C2);
      res[c] = num / den;
    }
    float* op = out + (size_t)n * IMG * IMG + (size_t)(y0 + r) * IMG + x0 + c4;
    *(float4*)op = make_float4(res[0], res[1], res[2], res[3]);
  }
}

extern "C" void kernel_launch(void* const* d_in, const int* in_sizes, int n_in,
                              void* d_out, int out_size, void* d_ws, size_t ws_size,
                              hipStream_t stream) {
  const float* img1 = (const float*)d_in[0];
  const float* img2 = (const float*)d_in[1];
  float* out = (float*)d_out;
  unsigned* ws = (unsigned*)d_ws;          // [0..1]: final max/min; [16..]: partials
  unsigned* part = ws + 16;
  int n = in_sizes[0];             // 32*1*512*512
  int batch = n / (IMG * IMG);     // 32

  // Gaussian window, center at ws/2 = 5.5 (asymmetric!), normalized
  W11 wv;
  double g[11], s = 0.0;
  for (int i = 0; i < 11; ++i) { double d = i - 5.5; g[i] = exp(-(d * d) / 4.5); s += g[i]; }
  for (int i = 0; i < 11; ++i) wv.w[i] = (float)(g[i] / s);

  minmax_part<<<MMB, 256, 0, stream>>>((const float4*)img1, n / 4, part);
  minmax_final<<<1, 256, 0, stream>>>(part, ws);
  dim3 grid(IMG / TW, IMG / TH, batch);
  ssim_k<<<grid, 512, 0, stream>>>(img1, img2, out, ws, wv);
}

// Round 4
// 149.120 us; speedup vs baseline: 2.1857x; 2.1857x over previous
//
#include <hip/hip_runtime.h>
#include <math.h>

#define IMG 512
#define TW 128     // output tile width
#define TH 16      // output tile height
#define RS 148     // LDS row stride floats = 37 granules (odd -> per-row bank-phase rotation)
#define NQ 36      // col-quads per intermediate row (cols x0-8 .. x0+135; halo = 2 full quads/side)
#define NVT (NQ * TH)   // 576 vertical tasks (1 row x 4 cols each)
#define MMB 1024   // minmax stage-1 blocks

struct W11 { float w[11]; };

__device__ __forceinline__ unsigned omap(float f) {
  unsigned b = __float_as_uint(f);
  return (b & 0x80000000u) ? ~b : (b | 0x80000000u);
}
__device__ __forceinline__ float ounmap(unsigned u) {
  return __uint_as_float((u & 0x80000000u) ? (u ^ 0x80000000u) : ~u);
}

// Stage 1: per-block partial min/max -> disjoint slots, no atomics.
__global__ __launch_bounds__(256) void minmax_part(const float4* __restrict__ img,
                                                   int n4, unsigned* __restrict__ part) {
  unsigned mx = 0u, mn = 0xFFFFFFFFu;
  int stride = gridDim.x * blockDim.x;
  for (int i = blockIdx.x * blockDim.x + threadIdx.x; i < n4; i += stride) {
    float4 v = img[i];
    unsigned a = omap(v.x), b = omap(v.y), c = omap(v.z), d = omap(v.w);
    mx = max(mx, max(max(a, b), max(c, d)));
    mn = min(mn, min(min(a, b), min(c, d)));
  }
  #pragma unroll
  for (int off = 32; off > 0; off >>= 1) {
    mx = max(mx, __shfl_down(mx, off));
    mn = min(mn, __shfl_down(mn, off));
  }
  __shared__ unsigned smx[4], smn[4];
  int lane = threadIdx.x & 63, wv = threadIdx.x >> 6;
  if (lane == 0) { smx[wv] = mx; smn[wv] = mn; }
  __syncthreads();
  if (threadIdx.x == 0) {
    mx = max(max(smx[0], smx[1]), max(smx[2], smx[3]));
    mn = min(min(smn[0], smn[1]), min(smn[2], smn[3]));
    part[2 * blockIdx.x]     = mx;
    part[2 * blockIdx.x + 1] = mn;
  }
}

// Stage 2: fold MMB partial pairs into ws[0]=max, ws[1]=min.
__global__ __launch_bounds__(256) void minmax_final(const unsigned* __restrict__ part,
                                                    unsigned* __restrict__ ws) {
  unsigned mx = 0u, mn = 0xFFFFFFFFu;
  for (int i = threadIdx.x; i < MMB; i += 256) {
    mx = max(mx, part[2 * i]);
    mn = min(mn, part[2 * i + 1]);
  }
  #pragma unroll
  for (int off = 32; off > 0; off >>= 1) {
    mx = max(mx, __shfl_down(mx, off));
    mn = min(mn, __shfl_down(mn, off));
  }
  __shared__ unsigned smx[4], smn[4];
  int lane = threadIdx.x & 63, wv = threadIdx.x >> 6;
  if (lane == 0) { smx[wv] = mx; smn[wv] = mn; }
  __syncthreads();
  if (threadIdx.x == 0) {
    ws[0] = max(max(smx[0], smx[1]), max(smx[2], smx[3]));
    ws[1] = min(min(smn[0], smn[1]), min(smn[2], smn[3]));
  }
}

// One vertical task: 11-tap v-conv of {a, b, a^2+b^2, a*b} for (1 row x 4 cols),
// result stored to LDS as 8 x b64 (consecutive lanes -> consecutive 4-float
// columns: the only write pattern measured conflict-free, round 0).
// Separate function so each call is its own liveness region (round-3 lesson:
// unrolled 2-task loop doubled live accumulators -> spill under the VGPR cap).
__device__ __forceinline__ void vtask(int t, int x0, int y0, bool y_full,
                                      const float* __restrict__ p1,
                                      const float* __restrict__ p2,
                                      const W11& wv,
                                      float (*V)[TH][RS]) {
  const int r = t / NQ;              // 0..15
  const int q = t - r * NQ;          // 0..35
  const int gx0 = x0 - 8 + 4 * q;    // multiple of 4; halo quads are fully OOB
  const int gy0 = y0 + r - 5;

  float a0x = 0.f, a0y = 0.f, a0z = 0.f, a0w = 0.f;   // mu1
  float a1x = 0.f, a1y = 0.f, a1z = 0.f, a1w = 0.f;   // mu2
  float a2x = 0.f, a2y = 0.f, a2z = 0.f, a2w = 0.f;   // a^2+b^2
  float a3x = 0.f, a3y = 0.f, a3z = 0.f, a3w = 0.f;   // a*b

#define VSTEP(k, a, b)                                                        \
  {                                                                           \
    float wk = wv.w[k];                                                       \
    a0x += wk * a.x; a0y += wk * a.y; a0z += wk * a.z; a0w += wk * a.w;       \
    a1x += wk * b.x; a1y += wk * b.y; a1z += wk * b.z; a1w += wk * b.w;       \
    float sx = a.x * a.x + b.x * b.x, sy = a.y * a.y + b.y * b.y;             \
    float sz = a.z * a.z + b.z * b.z, sw = a.w * a.w + b.w * b.w;             \
    a2x += wk * sx; a2y += wk * sy; a2z += wk * sz; a2w += wk * sw;           \
    float px = a.x * b.x, py = a.y * b.y, pz = a.z * b.z, pw = a.w * b.w;     \
    a3x += wk * px; a3y += wk * py; a3z += wk * pz; a3w += wk * pw;           \
  }

  if ((unsigned)gx0 < IMG) {
    if (y_full) {
      const float4* A = (const float4*)(p1 + (size_t)gy0 * IMG + gx0);
      const float4* B = (const float4*)(p2 + (size_t)gy0 * IMG + gx0);
      #pragma unroll
      for (int k = 0; k < 11; ++k) {
        float4 a = A[k * (IMG / 4)];
        float4 b = B[k * (IMG / 4)];
        VSTEP(k, a, b);
      }
    } else {
      #pragma unroll
      for (int k = 0; k < 11; ++k) {
        int row = gy0 + k;
        float4 a = make_float4(0.f, 0.f, 0.f, 0.f);
        float4 b = make_float4(0.f, 0.f, 0.f, 0.f);
        if ((unsigned)row < IMG) {
          a = *(const float4*)(p1 + (size_t)row * IMG + gx0);
          b = *(const float4*)(p2 + (size_t)row * IMG + gx0);
        }
        VSTEP(k, a, b);
      }
    }
  }
#undef VSTEP

  // b64 writes only (round-0-clean class). Stores end accumulator liveness.
  *(float2*)&V[0][r][4 * q]     = make_float2(a0x, a0y);
  *(float2*)&V[0][r][4 * q + 2] = make_float2(a0z, a0w);
  *(float2*)&V[1][r][4 * q]     = make_float2(a1x, a1y);
  *(float2*)&V[1][r][4 * q + 2] = make_float2(a1z, a1w);
  *(float2*)&V[2][r][4 * q]     = make_float2(a2x, a2y);
  *(float2*)&V[2][r][4 * q + 2] = make_float2(a2z, a2w);
  *(float2*)&V[3][r][4 * q]     = make_float2(a3x, a3y);
  *(float2*)&V[3][r][4 * q + 2] = make_float2(a3z, a3w);
}

// Fused SSIM, v-first, phase-balanced, b64-only LDS.
// launch_bounds(512,4): 128-VGPR cap -- the regime round 2 proved spill-free;
// (512,8)'s 64-cap caused the round-3 scratch disaster (432MB stack traffic).
__global__ __launch_bounds__(512, 4) void ssim_k(const float* __restrict__ img1,
                                                 const float* __restrict__ img2,
                                                 float* __restrict__ out,
                                                 const unsigned* __restrict__ ws,
                                                 W11 wv) {
  __shared__ float V[4][TH][RS];   // 37888 B -> 4 blocks/CU (LDS-wise)

  const int tid = threadIdx.x;
  const int bx = blockIdx.x, by = blockIdx.y, n = blockIdx.z;
  const float* p1 = img1 + (size_t)n * IMG * IMG;
  const float* p2 = img2 + (size_t)n * IMG * IMG;
  const int x0 = bx * TW;
  const int y0 = by * TH;

  // C1/C2 (scalar loads issued early; needed after the barrier)
  float L = ounmap(ws[0]) - ounmap(ws[1]);
  if (L == 0.f) L = 5.f;
  float C1 = 0.01f * L; C1 *= C1;
  float C2 = 0.03f * L; C2 *= C2;

  const bool y_full = (by > 0) & (by < IMG / TH - 1);

  // ---- vertical pass: 576 tasks on 512 threads. Everyone does task tid;
  // wave 0 (all 64 lanes active -> no divergence waste) does the 64 extras
  // in a separate branch AFTER the first task's stores (separate liveness).
  vtask(tid, x0, y0, y_full, p1, p2, wv, V);
  if (tid < 64) vtask(512 + tid, x0, y0, y_full, p1, p2, wv, V);

  __syncthreads();   // the only barrier

  // ---- horizontal pass: all 512 threads, thread = (1 row, 4 output cols).
  // Reads: 8 x b64 per field, consecutive lanes -> consecutive columns of the
  // SAME row (round-0-clean orientation; round-2's same-column-different-row
  // reads were the conflicting pattern).
  {
    const int r  = tid >> 5;           // 0..15
    const int c4 = (tid & 31) << 2;    // output col offset 0..124

    float acc[4][4];
    #pragma unroll
    for (int f = 0; f < 4; ++f)
      #pragma unroll
      for (int c = 0; c < 4; ++c) acc[f][c] = 0.f;

    float v[16];   // function scope, constant indices only (SROA-safe)
    #pragma unroll
    for (int f = 0; f < 4; ++f) {
      // window: intermediate local cols c4+2 .. c4+17; taps use c4+3 .. c4+16
      const float* row = &V[f][r][c4 + 2];
      float2 g0 = *(const float2*)(row + 0);
      float2 g1 = *(const float2*)(row + 2);
      float2 g2 = *(const float2*)(row + 4);
      float2 g3 = *(const float2*)(row + 6);
      float2 g4 = *(const float2*)(row + 8);
      float2 g5 = *(const float2*)(row + 10);
      float2 g6 = *(const float2*)(row + 12);
      float2 g7 = *(const float2*)(row + 14);
      v[0]  = g0.x; v[1]  = g0.y; v[2]  = g1.x; v[3]  = g1.y;
      v[4]  = g2.x; v[5]  = g2.y; v[6]  = g3.x; v[7]  = g3.y;
      v[8]  = g4.x; v[9]  = g4.y; v[10] = g5.x; v[11] = g5.y;
      v[12] = g6.x; v[13] = g6.y; v[14] = g7.x; v[15] = g7.y;
      // output col c taps v[c+1+k], k=0..10  (v[i] = local col c4+2+i)
      #pragma unroll
      for (int k = 0; k < 11; ++k) {
        float wk = wv.w[k];
        #pragma unroll
        for (int c = 0; c < 4; ++c) acc[f][c] += wk * v[c + 1 + k];
      }
    }

    float res[4];
    #pragma unroll
    for (int c = 0; c < 4; ++c) {
      float mu1 = acc[0][c], mu2 = acc[1][c];
      float mu1s = mu1 * mu1, mu2s = mu2 * mu2, mu12 = mu1 * mu2;
      float sS  = acc[2][c] - mu1s - mu2s;   // sigma1_sq + sigma2_sq
      float s12 = acc[3][c] - mu12;
      float num = (2.f * mu12 + C1) * (2.f * s12 + C2);
      float den = (mu1s + mu2s + C1) * (sS + C2);
      res[c] = num / den;
    }
    float* op = out + (size_t)n * IMG * IMG + (size_t)(y0 + r) * IMG + x0 + c4;
    *(float4*)op = make_float4(res[0], res[1], res[2], res[3]);
  }
}

extern "C" void kernel_launch(void* const* d_in, const int* in_sizes, int n_in,
                              void* d_out, int out_size, void* d_ws, size_t ws_size,
                              hipStream_t stream) {
  const float* img1 = (const float*)d_in[0];
  const float* img2 = (const float*)d_in[1];
  float* out = (float*)d_out;
  unsigned* ws = (unsigned*)d_ws;          // [0..1]: final max/min; [16..]: partials
  unsigned* part = ws + 16;
  int n = in_sizes[0];             // 32*1*512*512
  int batch = n / (IMG * IMG);     // 32

  // Gaussian window, center at ws/2 = 5.5 (asymmetric!), normalized
  W11 wv;
  double g[11], s = 0.0;
  for (int i = 0; i < 11; ++i) { double d = i - 5.5; g[i] = exp(-(d * d) / 4.5); s += g[i]; }
  for (int i = 0; i < 11; ++i) wv.w[i] = (float)(g[i] / s);

  minmax_part<<<MMB, 256, 0, stream>>>((const float4*)img1, n / 4, part);
  minmax_final<<<1, 256, 0, stream>>>(part, ws);
  dim3 grid(IMG / TW, IMG / TH, batch);
  ssim_k<<<grid, 512, 0, stream>>>(img1, img2, out, ws, wv);
}

// Round 5
// 138.058 us; speedup vs baseline: 2.3608x; 1.0801x over previous
//
#include <hip/hip_runtime.h>
#include <math.h>

#define IMG 512
#define TW 128     // output tile width
#define TH 16      // output tile height
#define RS 150     // LDS row stride floats: 150%32=22, gcd(22,32)=2 -> 16 rows cover all
                   // 16 even bank residues exactly once (h-read conflict killer)
#define NQ 36      // col-quads per intermediate row (cols x0-8 .. x0+135; halo = 2 full quads/side)
#define MMB 1024   // minmax stage-1 blocks

struct W11 { float w[11]; };

__device__ __forceinline__ unsigned omap(float f) {
  unsigned b = __float_as_uint(f);
  return (b & 0x80000000u) ? ~b : (b | 0x80000000u);
}
__device__ __forceinline__ float ounmap(unsigned u) {
  return __uint_as_float((u & 0x80000000u) ? (u ^ 0x80000000u) : ~u);
}

// Stage 1: per-block partial min/max -> disjoint slots, no atomics.
__global__ __launch_bounds__(256) void minmax_part(const float4* __restrict__ img,
                                                   int n4, unsigned* __restrict__ part) {
  unsigned mx = 0u, mn = 0xFFFFFFFFu;
  int stride = gridDim.x * blockDim.x;
  for (int i = blockIdx.x * blockDim.x + threadIdx.x; i < n4; i += stride) {
    float4 v = img[i];
    unsigned a = omap(v.x), b = omap(v.y), c = omap(v.z), d = omap(v.w);
    mx = max(mx, max(max(a, b), max(c, d)));
    mn = min(mn, min(min(a, b), min(c, d)));
  }
  #pragma unroll
  for (int off = 32; off > 0; off >>= 1) {
    mx = max(mx, __shfl_down(mx, off));
    mn = min(mn, __shfl_down(mn, off));
  }
  __shared__ unsigned smx[4], smn[4];
  int lane = threadIdx.x & 63, wv = threadIdx.x >> 6;
  if (lane == 0) { smx[wv] = mx; smn[wv] = mn; }
  __syncthreads();
  if (threadIdx.x == 0) {
    mx = max(max(smx[0], smx[1]), max(smx[2], smx[3]));
    mn = min(min(smn[0], smn[1]), min(smn[2], smn[3]));
    part[2 * blockIdx.x]     = mx;
    part[2 * blockIdx.x + 1] = mn;
  }
}

// Stage 2: fold MMB partial pairs into ws[0]=max, ws[1]=min.
__global__ __launch_bounds__(256) void minmax_final(const unsigned* __restrict__ part,
                                                    unsigned* __restrict__ ws) {
  unsigned mx = 0u, mn = 0xFFFFFFFFu;
  for (int i = threadIdx.x; i < MMB; i += 256) {
    mx = max(mx, part[2 * i]);
    mn = min(mn, part[2 * i + 1]);
  }
  #pragma unroll
  for (int off = 32; off > 0; off >>= 1) {
    mx = max(mx, __shfl_down(mx, off));
    mn = min(mn, __shfl_down(mn, off));
  }
  __shared__ unsigned smx[4], smn[4];
  int lane = threadIdx.x & 63, wv = threadIdx.x >> 6;
  if (lane == 0) { smx[wv] = mx; smn[wv] = mn; }
  __syncthreads();
  if (threadIdx.x == 0) {
    ws[0] = max(max(smx[0], smx[1]), max(smx[2], smx[3]));
    ws[1] = min(min(smn[0], smn[1]), min(smn[2], smn[3]));
  }
}

// One vertical task: 11-tap v-conv of {a, b, a^2+b^2, a*b} for (1 row x 4 cols),
// stored to LDS as 8 x b64, consecutive lanes -> consecutive addresses
// (measured conflict-free in rounds 0 and 4).
// Separate function so each call is its own liveness region (round-3 lesson:
// unrolled 2-task loop doubled live accumulators -> spill under the VGPR cap).
__device__ __forceinline__ void vtask(int t, int x0, int y0, bool y_full,
                                      const float* __restrict__ p1,
                                      const float* __restrict__ p2,
                                      const W11& wv,
                                      float (*V)[TH][RS]) {
  const int r = t / NQ;              // 0..15
  const int q = t - r * NQ;          // 0..35
  const int gx0 = x0 - 8 + 4 * q;    // multiple of 4; halo quads are fully OOB
  const int gy0 = y0 + r - 5;

  float a0x = 0.f, a0y = 0.f, a0z = 0.f, a0w = 0.f;   // mu1
  float a1x = 0.f, a1y = 0.f, a1z = 0.f, a1w = 0.f;   // mu2
  float a2x = 0.f, a2y = 0.f, a2z = 0.f, a2w = 0.f;   // a^2+b^2
  float a3x = 0.f, a3y = 0.f, a3z = 0.f, a3w = 0.f;   // a*b

#define VSTEP(k, a, b)                                                        \
  {                                                                           \
    float wk = wv.w[k];                                                       \
    a0x += wk * a.x; a0y += wk * a.y; a0z += wk * a.z; a0w += wk * a.w;       \
    a1x += wk * b.x; a1y += wk * b.y; a1z += wk * b.z; a1w += wk * b.w;       \
    float sx = a.x * a.x + b.x * b.x, sy = a.y * a.y + b.y * b.y;             \
    float sz = a.z * a.z + b.z * b.z, sw = a.w * a.w + b.w * b.w;             \
    a2x += wk * sx; a2y += wk * sy; a2z += wk * sz; a2w += wk * sw;           \
    float px = a.x * b.x, py = a.y * b.y, pz = a.z * b.z, pw = a.w * b.w;     \
    a3x += wk * px; a3y += wk * py; a3z += wk * pz; a3w += wk * pw;           \
  }

  if ((unsigned)gx0 < IMG) {
    if (y_full) {
      const float4* A = (const float4*)(p1 + (size_t)gy0 * IMG + gx0);
      const float4* B = (const float4*)(p2 + (size_t)gy0 * IMG + gx0);
      #pragma unroll
      for (int k = 0; k < 11; ++k) {
        float4 a = A[k * (IMG / 4)];
        float4 b = B[k * (IMG / 4)];
        VSTEP(k, a, b);
      }
    } else {
      #pragma unroll
      for (int k = 0; k < 11; ++k) {
        int row = gy0 + k;
        float4 a = make_float4(0.f, 0.f, 0.f, 0.f);
        float4 b = make_float4(0.f, 0.f, 0.f, 0.f);
        if ((unsigned)row < IMG) {
          a = *(const float4*)(p1 + (size_t)row * IMG + gx0);
          b = *(const float4*)(p2 + (size_t)row * IMG + gx0);
        }
        VSTEP(k, a, b);
      }
    }
  }
#undef VSTEP

  // b64 writes, consecutive lanes -> consecutive addresses. Stores end
  // accumulator liveness.
  *(float2*)&V[0][r][4 * q]     = make_float2(a0x, a0y);
  *(float2*)&V[0][r][4 * q + 2] = make_float2(a0z, a0w);
  *(float2*)&V[1][r][4 * q]     = make_float2(a1x, a1y);
  *(float2*)&V[1][r][4 * q + 2] = make_float2(a1z, a1w);
  *(float2*)&V[2][r][4 * q]     = make_float2(a2x, a2y);
  *(float2*)&V[2][r][4 * q + 2] = make_float2(a2z, a2w);
  *(float2*)&V[3][r][4 * q]     = make_float2(a3x, a3y);
  *(float2*)&V[3][r][4 * q + 2] = make_float2(a3z, a3w);
}

// Fused SSIM, v-first, phase-balanced, b64-only LDS, conflict-free both passes.
// launch_bounds(512,4): 128-VGPR cap -- the proven spill-free regime (round 3's
// (512,8) 64-cap caused 432MB of scratch traffic; round 4 at (512,4) was clean).
// Round-4 lesson: h-read mapping (same row, 16B lane stride) was a 4-way bank
// conflict (14.8M cycles). Fix: r = tid&15 (lanes span all 16 rows) + RS=150
// (22 mod 32, gcd 2) -> every b64 read touches each bank exactly twice (free).
__global__ __launch_bounds__(512, 4) void ssim_k(const float* __restrict__ img1,
                                                 const float* __restrict__ img2,
                                                 float* __restrict__ out,
                                                 const unsigned* __restrict__ ws,
                                                 W11 wv) {
  __shared__ float V[4][TH][RS];   // 38400 B -> 4 blocks/CU (LDS-wise)

  const int tid = threadIdx.x;
  const int bx = blockIdx.x, by = blockIdx.y, n = blockIdx.z;
  const float* p1 = img1 + (size_t)n * IMG * IMG;
  const float* p2 = img2 + (size_t)n * IMG * IMG;
  const int x0 = bx * TW;
  const int y0 = by * TH;

  // C1/C2 (scalar loads issued early; needed after the barrier)
  float L = ounmap(ws[0]) - ounmap(ws[1]);
  if (L == 0.f) L = 5.f;
  float C1 = 0.01f * L; C1 *= C1;
  float C2 = 0.03f * L; C2 *= C2;

  const bool y_full = (by > 0) & (by < IMG / TH - 1);

  // ---- vertical pass: 576 tasks on 512 threads. Everyone does task tid;
  // wave 0 (full 64-lane density) does the 64 extras in a separate branch
  // AFTER the first task's stores (separate liveness region).
  vtask(tid, x0, y0, y_full, p1, p2, wv, V);
  if (tid < 64) vtask(512 + tid, x0, y0, y_full, p1, p2, wv, V);

  __syncthreads();   // the only barrier

  // ---- horizontal pass: all 512 threads, thread = (1 row, 4 output cols).
  // Mapping r = tid&15: a 32-lane half covers 16 rows x 2 col-quads; with
  // RS=150 the 16 row bases hit all 16 even bank residues once -> every b64
  // read is exactly 2 lanes/bank (free). All 8 window reads share the spread
  // (uniform shift).
  {
    const int r  = tid & 15;           // row 0..15
    const int c4 = (tid >> 4) << 2;    // output col offset 0..124

    float acc[4][4];
    #pragma unroll
    for (int f = 0; f < 4; ++f)
      #pragma unroll
      for (int c = 0; c < 4; ++c) acc[f][c] = 0.f;

    float v[16];   // function scope, constant indices only (SROA-safe)
    #pragma unroll
    for (int f = 0; f < 4; ++f) {
      // window: intermediate local cols c4+2 .. c4+17; taps use c4+3 .. c4+16
      const float* row = &V[f][r][c4 + 2];
      float2 g0 = *(const float2*)(row + 0);
      float2 g1 = *(const float2*)(row + 2);
      float2 g2 = *(const float2*)(row + 4);
      float2 g3 = *(const float2*)(row + 6);
      float2 g4 = *(const float2*)(row + 8);
      float2 g5 = *(const float2*)(row + 10);
      float2 g6 = *(const float2*)(row + 12);
      float2 g7 = *(const float2*)(row + 14);
      v[0]  = g0.x; v[1]  = g0.y; v[2]  = g1.x; v[3]  = g1.y;
      v[4]  = g2.x; v[5]  = g2.y; v[6]  = g3.x; v[7]  = g3.y;
      v[8]  = g4.x; v[9]  = g4.y; v[10] = g5.x; v[11] = g5.y;
      v[12] = g6.x; v[13] = g6.y; v[14] = g7.x; v[15] = g7.y;
      // output col c taps v[c+1+k], k=0..10  (v[i] = local col c4+2+i)
      #pragma unroll
      for (int k = 0; k < 11; ++k) {
        float wk = wv.w[k];
        #pragma unroll
        for (int c = 0; c < 4; ++c) acc[f][c] += wk * v[c + 1 + k];
      }
    }

    float res[4];
    #pragma unroll
    for (int c = 0; c < 4; ++c) {
      float mu1 = acc[0][c], mu2 = acc[1][c];
      float mu1s = mu1 * mu1, mu2s = mu2 * mu2, mu12 = mu1 * mu2;
      float sS  = acc[2][c] - mu1s - mu2s;   // sigma1_sq + sigma2_sq
      float s12 = acc[3][c] - mu12;
      float num = (2.f * mu12 + C1) * (2.f * s12 + C2);
      float den = (mu1s + mu2s + C1) * (sS + C2);
      res[c] = num / den;
    }
    float* op = out + (size_t)n * IMG * IMG + (size_t)(y0 + r) * IMG + x0 + c4;
    *(float4*)op = make_float4(res[0], res[1], res[2], res[3]);
  }
}

extern "C" void kernel_launch(void* const* d_in, const int* in_sizes, int n_in,
                              void* d_out, int out_size, void* d_ws, size_t ws_size,
                              hipStream_t stream) {
  const float* img1 = (const float*)d_in[0];
  const float* img2 = (const float*)d_in[1];
  float* out = (float*)d_out;
  unsigned* ws = (unsigned*)d_ws;          // [0..1]: final max/min; [16..]: partials
  unsigned* part = ws + 16;
  int n = in_sizes[0];             // 32*1*512*512
  int batch = n / (IMG * IMG);     // 32

  // Gaussian window, center at ws/2 = 5.5 (asymmetric!), normalized
  W11 wv;
  double g[11], s = 0.0;
  for (int i = 0; i < 11; ++i) { double d = i - 5.5; g[i] = exp(-(d * d) / 4.5); s += g[i]; }
  for (int i = 0; i < 11; ++i) wv.w[i] = (float)(g[i] / s);

  minmax_part<<<MMB, 256, 0, stream>>>((const float4*)img1, n / 4, part);
  minmax_final<<<1, 256, 0, stream>>>(part, ws);
  dim3 grid(IMG / TW, IMG / TH, batch);
  ssim_k<<<grid, 512, 0, stream>>>(img1, img2, out, ws, wv);
}